// Round 6
// baseline (206.404 us; speedup 1.0000x reference)
//
#include <hip/hip_runtime.h>
#include <hip/hip_bf16.h>
#include <math.h>

#define DIM   768
#define CA    192

typedef __attribute__((ext_vector_type(8))) short short8;
typedef __attribute__((ext_vector_type(4))) float f32x4;

static __device__ __forceinline__ short f2bf(float f) {
    union { __hip_bfloat16 b; short s; } u;
    u.b = __float2bfloat16(f);
    return u.s;
}
static __device__ __forceinline__ float gelu_exact(float x) {
    return 0.5f * x * (1.0f + erff(x * 0.70710678118654752440f));
}
// async global->LDS DMA, 16B per lane; lds base must be wave-uniform.
static __device__ __forceinline__ void ld16(void* lds, const void* gsrc) {
    __builtin_amdgcn_global_load_lds((const __attribute__((address_space(1))) void*)gsrc,
                                     (__attribute__((address_space(3))) void*)lds, 16, 0, 0);
}

// ---------------------------------------------------------------------------
// Prep: w1 (768,192) -> w1T (192,768) bf16; w2 (192,768) -> w2T (768,192) bf16
// ---------------------------------------------------------------------------
__global__ void prep_kernel(const float* __restrict__ w1, const float* __restrict__ w2,
                            short* __restrict__ w1T, short* __restrict__ w2T) {
    int idx = blockIdx.x * 256 + threadIdx.x;
    if (idx < CA * DIM) {
        int n = idx / DIM, k = idx - n * DIM;
        w1T[idx] = f2bf(w1[k * CA + n]);
        int n2 = idx / CA, k2 = idx - n2 * CA;
        w2T[idx] = f2bf(w2[k2 * DIM + n2]);
    }
}

// ---------------------------------------------------------------------------
// FUSED kernel: one block = (l, hm) = 64 rows of bt for one token l.
//   Phase 1: h = x@w1+b1 (64x192, K=768, BK=32, 24 iters). B1 via 3-stage
//     global_load_lds pipeline (2-iter lead, counted vmcnt, 1 barrier/iter);
//     A via reg-staged f32 loads (3-slot, 3-iter lead) + cvt + swizzled
//     ds_write. BUGFIX vs prev round: prologue reloads slot 0 with stage 3
//     after WRITE_A(0) consumes stage 0 (stage 3 was previously never
//     loaded -> wrong A data for one K-stage).
//   Epilogue: temporal mix + gelu -> g (bf16) written to LDS gA (swizzled
//     for phase-2 fragment reads). l==1 also stores g0 (token-0 g) to global
//     scratch (own-block round-trip; visible via vmcnt(0) drain).
//   Phase 2: out = x + g@w2 + b2 for this block's 64 rows, N=768 in 12
//     chunks of 64 cols; w2T chunk DMA double-buffered in the dead phase-1
//     pipe LDS; x residual re-read (L3-hot); out streamed. l==1 runs phase 2
//     twice (second pass: gA restaged from g0 scratch, out rows = token 0).
// LDS: pipe 49152 B + gA 24576 B = 73728 B -> 2 blocks/CU; all 392 blocks
// co-resident -> phase-1 (read-bound) overlaps phase-2 (write-bound) across
// blocks; no inter-kernel serialization.
// vmcnt accounting (per-wave in-order queue; issue order pinned by asm
// memory clobbers: per iter {3 B-DMA, then 2 A-loads}):
//   prologue issues A0,A1,A2,B0,B1,A3 (A0 retired by WRITE_A(0)'s wait)
//   t=0: queue A1,A2,B0,B1,A3 (12) -> need B0 -> vmcnt(5)
//   t=1..20: queue A(t+1),B(t),A(t+2),B(t+1),A(t+3) (12) -> vmcnt(7)
//   t=21: vmcnt(5); t=22: vmcnt(3); t=23: vmcnt(0)
// Swizzles (both-sides, rule 21):
//   ph1 (rows of 4 chunks):  slot = q ^ ((m>>1)&3)   -> 2-way (free)
//   ph2 (rows of 24 chunks): slot = q ^ (m&7)        -> 2-way (free)
// ---------------------------------------------------------------------------
__global__ __launch_bounds__(256, 2) void fused_kernel(
        const float* __restrict__ x,    const short* __restrict__ w1T,
        const float* __restrict__ b1,   const float* __restrict__ conv_w,
        const float* __restrict__ conv_b, const short* __restrict__ w2T,
        const float* __restrict__ b2,   short* __restrict__ g0s,
        float* __restrict__ out) {
    __shared__ __align__(16) short ldsbuf[36864];   // 73728 B
    short* pipe = ldsbuf;                // ph1: 3 x 8192 shorts; ph2: B2 2 x 12288
    short* gA   = ldsbuf + 24576;        // 64 x 192 bf16, swizzled

    const int tid = threadIdx.x;
    const int bx  = blockIdx.x;
    const int l   = (bx >> 1) + 1;
    const int hm  = bx & 1;
    const int R0  = l * 128 + hm * 64;

    const int wave = tid >> 6, lane = tid & 63;
    const int wm = wave >> 1, wn = wave & 1;
    const int lm = lane & 15, lg = lane >> 4;

    // ---- phase 1 setup -----------------------------------------------------
    // B1 DMA: 12 instrs/stage (192 rows x 4 chunks), 3 per wave.
    const short* b1src[3];
    int b1lds[3];
    #pragma unroll
    for (int j = 0; j < 3; j++) {
        int s = (wave * 3 + j) * 64 + lane;
        int m = s >> 2, q = (s & 3) ^ ((m >> 1) & 3);
        b1src[j] = w1T + (size_t)m * DIM + q * 8;
        b1lds[j] = 2048 + (wave * 3 + j) * 512;     // shorts, stage-relative
    }
    // A reg-stage: thread owns row ar, logical chunk q0 (8 consecutive k).
    const int ar    = tid >> 2;
    const int q0    = tid & 3;
    const int aslot = q0 ^ ((ar >> 1) & 3);
    const float* xrow = x + (size_t)(R0 + ar) * DIM + q0 * 8;

    f32x4 acc[2][6] = {};
    f32x4 a_regs[3][2];

    // prologue: A(0..2) loads; B(0..1) DMA; write A(0); reload slot0 = A(3)
    #pragma unroll
    for (int st = 0; st < 3; st++) {
        a_regs[st][0] = *(const f32x4*)(xrow + st * 32);
        a_regs[st][1] = *(const f32x4*)(xrow + st * 32 + 4);
    }
    asm volatile("" ::: "memory");                  // pin: A-loads before B-DMA
    #pragma unroll
    for (int st = 0; st < 2; st++)
        #pragma unroll
        for (int j = 0; j < 3; j++)
            ld16(&pipe[st * 8192 + b1lds[j]], b1src[j] + st * 32);
    asm volatile("" ::: "memory");                  // pin: B-DMA before A3 reload
    {   // WRITE_A(0)
        short8 v;
        #pragma unroll
        for (int e = 0; e < 4; e++) { v[e] = f2bf(a_regs[0][0][e]); v[4 + e] = f2bf(a_regs[0][1][e]); }
        *(short8*)&pipe[0 * 8192 + ar * 32 + aslot * 8] = v;
    }
    a_regs[0][0] = *(const f32x4*)(xrow + 96);      // stage 3 (BUGFIX)
    a_regs[0][1] = *(const f32x4*)(xrow + 100);

    // ---- phase 1 main loop -------------------------------------------------
    #pragma unroll
    for (int t = 0; t < 24; t++) {
        if      (t == 0)  asm volatile("s_waitcnt vmcnt(5) lgkmcnt(0)" ::: "memory");
        else if (t <= 20) asm volatile("s_waitcnt vmcnt(7) lgkmcnt(0)" ::: "memory");
        else if (t == 21) asm volatile("s_waitcnt vmcnt(5) lgkmcnt(0)" ::: "memory");
        else if (t == 22) asm volatile("s_waitcnt vmcnt(3) lgkmcnt(0)" ::: "memory");
        else              asm volatile("s_waitcnt vmcnt(0) lgkmcnt(0)" ::: "memory");
        __builtin_amdgcn_s_barrier();

        if (t <= 21) {
            #pragma unroll
            for (int j = 0; j < 3; j++)
                ld16(&pipe[((t + 2) % 3) * 8192 + b1lds[j]], b1src[j] + (t + 2) * 32);
        }
        asm volatile("" ::: "memory");              // pin: DMA before this iter's loads

        const short* S = &pipe[(t % 3) * 8192];
        short8 af[2], bf[6];
        #pragma unroll
        for (int i2 = 0; i2 < 2; i2++) {
            int r = wm * 32 + i2 * 16 + lm;
            af[i2] = *(const short8*)&S[r * 32 + (lg ^ ((r >> 1) & 3)) * 8];
        }
        #pragma unroll
        for (int j = 0; j < 6; j++) {
            int rB = wn * 96 + j * 16 + lm;
            bf[j] = *(const short8*)&S[2048 + rB * 32 + (lg ^ ((rB >> 1) & 3)) * 8];
        }
        #pragma unroll
        for (int i2 = 0; i2 < 2; i2++)
            #pragma unroll
            for (int j = 0; j < 6; j++)
                acc[i2][j] = __builtin_amdgcn_mfma_f32_16x16x32_bf16(af[i2], bf[j], acc[i2][j], 0, 0, 0);

        if (t <= 22) {                              // WRITE_A(t+1): slot (t+1)%3 = stage t+1
            const int sl = (t + 1) % 3;
            short8 v;
            #pragma unroll
            for (int e = 0; e < 4; e++) { v[e] = f2bf(a_regs[sl][0][e]); v[4 + e] = f2bf(a_regs[sl][1][e]); }
            *(short8*)&pipe[sl * 8192 + ar * 32 + aslot * 8] = v;
            if (t <= 19) {                          // reload slot with stage t+4
                a_regs[sl][0] = *(const f32x4*)(xrow + (t + 4) * 32);
                a_regs[sl][1] = *(const f32x4*)(xrow + (t + 4) * 32 + 4);
            }
        }
    }

    // ---- epilogue: temporal mix + gelu -> gA (LDS) [+ g0s for l==1] --------
    const int g1 = lg & 1;
    #pragma unroll
    for (int j = 0; j < 6; j++) {
        const int c = wn * 96 + j * 16 + lm;
        const float b1c = b1[c];
        const float cw0 = conv_w[c * 3 + 0];
        const float cw1 = conv_w[c * 3 + 1];
        const float cw2 = conv_w[c * 3 + 2];
        const float cb  = conv_b[c];
        #pragma unroll
        for (int i2 = 0; i2 < 2; i2++) {
            float hv[4];
            #pragma unroll
            for (int r = 0; r < 4; r++) hv[r] = acc[i2][j][r] + b1c;
            float partial = 0.f;
            #pragma unroll
            for (int r = 0; r < 4; r++) {
                const int t = g1 * 4 + r;
                const float tf = (float)t;
                float coef = tf * cw1 - (7.0f - tf);
                if (t <= 6) coef += (tf + 1.0f) * cw0;
                if (t >= 1) coef += (tf - 1.0f) * cw2;
                partial += coef * hv[r];
            }
            const float full = partial + __shfl_xor(partial, 16);
            const float res = cb + full * (1.0f / 28.0f);
            const int mrow = wm * 32 + i2 * 16 + lg * 4;        // local row
            #pragma unroll
            for (int r = 0; r < 4; r++) {
                const int m = mrow + r;
                const int slot = (c >> 3) ^ (m & 7);
                gA[m * 192 + slot * 8 + (c & 7)] = f2bf(gelu_exact(hv[r] + res));
            }
            if (l == 1) {                            // token-0 g: gelu(h), no res
                #pragma unroll
                for (int r = 0; r < 4; r++)
                    g0s[(size_t)(hm * 64 + mrow + r) * CA + c] = f2bf(gelu_exact(hv[r]));
            }
        }
    }

    // ---- phase 2: out = x + g @ w2 + b2 ------------------------------------
    // chunk DMA mapping: 24 instrs/stage (64 rows x 24 chunks), 6 per wave.
    int b2off[6], b2lds[6];
    #pragma unroll
    for (int j = 0; j < 6; j++) {
        int s = (wave * 6 + j) * 64 + lane;
        int m = s / 24, q = s - m * 24;
        b2off[j] = m * CA + (q ^ (m & 7)) * 8;
        b2lds[j] = (wave * 6 + j) * 512;            // shorts
    }

    const int npass = (l == 1) ? 2 : 1;
    for (int pass = 0; pass < npass; pass++) {
        const int RO = pass ? hm * 64 : R0;
        if (pass == 1) {
            // drain pass-0 reads + g0 stores (own-block L2 round-trip), then restage gA
            asm volatile("s_waitcnt vmcnt(0) lgkmcnt(0)" ::: "memory");
            __builtin_amdgcn_s_barrier();
            #pragma unroll
            for (int j = 0; j < 6; j++)
                ld16(&gA[b2lds[j]], g0s + (size_t)hm * 64 * CA + b2off[j]);
        }
        // prologue: chunk 0 into buf 0
        #pragma unroll
        for (int j = 0; j < 6; j++)
            ld16(&pipe[b2lds[j]], w2T + b2off[j]);

        #pragma unroll
        for (int nc = 0; nc < 12; nc++) {
            asm volatile("s_waitcnt vmcnt(0) lgkmcnt(0)" ::: "memory");
            __builtin_amdgcn_s_barrier();
            if (nc < 11) {
                #pragma unroll
                for (int j = 0; j < 6; j++)
                    ld16(&pipe[((nc + 1) & 1) * 12288 + b2lds[j]],
                         w2T + (size_t)(nc + 1) * 64 * CA + b2off[j]);
            }
            asm volatile("" ::: "memory");

            // residual x loads for this chunk (issue early, overlap with MFMA)
            float xv[2][2][4];
            #pragma unroll
            for (int i2 = 0; i2 < 2; i2++)
                #pragma unroll
                for (int j2 = 0; j2 < 2; j2++) {
                    const int col = nc * 64 + wn * 32 + j2 * 16 + lm;
                    #pragma unroll
                    for (int r = 0; r < 4; r++)
                        xv[i2][j2][r] = x[(size_t)(RO + wm * 32 + i2 * 16 + lg * 4 + r) * DIM + col];
                }

            const short* B2 = &pipe[(nc & 1) * 12288];
            f32x4 acc2[2][2] = {};
            #pragma unroll
            for (int s2 = 0; s2 < 6; s2++) {
                short8 af2[2], bf2[2];
                #pragma unroll
                for (int i2 = 0; i2 < 2; i2++) {
                    int r = wm * 32 + i2 * 16 + lm;
                    af2[i2] = *(const short8*)&gA[r * 192 + (((s2 * 4 + lg) ^ (r & 7))) * 8];
                }
                #pragma unroll
                for (int j2 = 0; j2 < 2; j2++) {
                    int rn = wn * 32 + j2 * 16 + lm;
                    bf2[j2] = *(const short8*)&B2[rn * 192 + (((s2 * 4 + lg) ^ (rn & 7))) * 8];
                }
                #pragma unroll
                for (int i2 = 0; i2 < 2; i2++)
                    #pragma unroll
                    for (int j2 = 0; j2 < 2; j2++)
                        acc2[i2][j2] = __builtin_amdgcn_mfma_f32_16x16x32_bf16(af2[i2], bf2[j2], acc2[i2][j2], 0, 0, 0);
            }
            #pragma unroll
            for (int i2 = 0; i2 < 2; i2++)
                #pragma unroll
                for (int j2 = 0; j2 < 2; j2++) {
                    const int col = nc * 64 + wn * 32 + j2 * 16 + lm;
                    const float bias = b2[col];
                    #pragma unroll
                    for (int r = 0; r < 4; r++)
                        out[(size_t)(RO + wm * 32 + i2 * 16 + lg * 4 + r) * DIM + col] =
                            acc2[i2][j2][r] + xv[i2][j2][r] + bias;
                }
        }
    }
}

// ---------------------------------------------------------------------------
extern "C" void kernel_launch(void* const* d_in, const int* in_sizes, int n_in,
                              void* d_out, int out_size, void* d_ws, size_t ws_size,
                              hipStream_t stream) {
    (void)in_sizes; (void)n_in; (void)out_size; (void)ws_size;
    const float* x      = (const float*)d_in[0];
    const float* w1     = (const float*)d_in[1];
    const float* b1     = (const float*)d_in[2];
    const float* conv_w = (const float*)d_in[3];
    const float* conv_b = (const float*)d_in[4];
    const float* w2     = (const float*)d_in[5];
    const float* b2     = (const float*)d_in[6];
    float* out = (float*)d_out;

    char* ws = (char*)d_ws;
    short* w1T = (short*)ws;                           // 294,912 B
    short* w2T = (short*)(ws + 294912);                // 294,912 B
    short* g0s = (short*)(ws + 589824);                // 128*192*2 = 49,152 B

    prep_kernel<<<(CA * DIM + 255) / 256, 256, 0, stream>>>(w1, w2, w1T, w2T);
    fused_kernel<<<392, 256, 0, stream>>>(x, w1T, b1, conv_w, conv_b, w2T, b2, g0s, out);
}